// Round 4
// baseline (83.395 us; speedup 1.0000x reference)
//
#include <hip/hip_runtime.h>
#include <stdint.h>

#define TT 128
#define BB 4096
#define HH 64
#define BC 16     // batch rows per block
#define HSTR 72   // h LDS row stride (bf16 shorts): 144B rows, 16B aligned

typedef __attribute__((ext_vector_type(8))) short bf16x8;
typedef __attribute__((ext_vector_type(4))) float f32x4;

static __device__ __forceinline__ short f2bf(float f) {  // RNE, one-time W convert
  uint32_t u = __builtin_bit_cast(uint32_t, f);
  u += 0x7fffu + ((u >> 16) & 1u);
  return (short)(u >> 16);
}
static __device__ __forceinline__ uint32_t cvtpk(float a, float b) {
  uint32_t r;
  asm("v_cvt_pk_bf16_f32 %0, %1, %2" : "=v"(r) : "v"(a), "v"(b));
  return r;  // lo16 = bf16(a), hi16 = bf16(b)
}
static __device__ __forceinline__ float rcpf(float x) { return __builtin_amdgcn_rcpf(x); }
static __device__ __forceinline__ float sigm(float x) { return rcpf(1.0f + __expf(-x)); }
static __device__ __forceinline__ float tanhf_fast(float x) {
  float e = __expf(2.0f * x);
  return 1.0f - 2.0f * rcpf(e + 1.0f);
}

// lgkm-only barrier: LDS ops drain, global prefetch loads stay in flight.
static __device__ __forceinline__ void block_sync_lds() {
  asm volatile("" ::: "memory");
  asm volatile("s_waitcnt lgkmcnt(0)" ::: "memory");
  __builtin_amdgcn_s_barrier();
  asm volatile("" ::: "memory");
}

__global__ __launch_bounds__(256) void gru_fused(
    const float* __restrict__ Hseq, const float* __restrict__ W_ih,
    const float* __restrict__ W_hh, const float* __restrict__ b_ih,
    const float* __restrict__ b_hh, const float* __restrict__ W_out,
    const float* __restrict__ b_out, float* __restrict__ out) {
  __shared__ __align__(16) short hsh[2][BC][HSTR];  // bf16 h, double buffered (only LDS traffic)
  __shared__ float psum[4][BC];

  const int tid = threadIdx.x;
  const int w   = tid >> 6;    // wave 0..3 = gate-row chunk gw: j in [16w, 16w+16)
  const int l   = tid & 63;
  const int llo = l & 15;      // batch col (B/D frags) or gate row (A frag)
  const int lhi = l >> 4;
  const int k0  = lhi * 8;
  const int bbase = blockIdx.x * BC;

  // ---- persistent W A-fragments (bf16): both W_ih and W_hh (48 VGPRs) ----
  bf16x8 wih[3][2], whh[3][2];
#pragma unroll
  for (int c = 0; c < 3; ++c) {
    const int grow = 64 * c + 16 * w + llo;
#pragma unroll
    for (int hf = 0; hf < 2; ++hf) {
      const float* p = &W_ih[grow * 64 + hf * 32 + k0];
      const float* q = &W_hh[grow * 64 + hf * 32 + k0];
      bf16x8 a, b;
#pragma unroll
      for (int i = 0; i < 8; ++i) { a[i] = f2bf(p[i]); b[i] = f2bf(q[i]); }
      wih[c][hf] = a;
      whh[c][hf] = b;
    }
  }

  // ---- per-lane bias fragments (D rows j = 16w + 4*lhi + r) ----
  f32x4 biasR, biasZ, biasXN, biasHN;
#pragma unroll
  for (int r = 0; r < 4; ++r) {
    const int j = 16 * w + 4 * lhi + r;
    biasR[r]  = b_ih[j] + b_hh[j];
    biasZ[r]  = b_ih[64 + j] + b_hh[64 + j];
    biasXN[r] = b_ih[128 + j];
    biasHN[r] = b_hh[128 + j];
  }

  // zero h buffer 0 (h0 = 0)
  for (int i = tid; i < (BC * HSTR) / 2; i += 256) ((int*)hsh[0])[i] = 0;

  // ---- x[0]: load, convert, build x-side tiles for t=0 (registers, no LDS) ----
  const float* xroot = Hseq + (size_t)(bbase + llo) * HH + k0;  // per-lane t=0 base
  f32x4 xq0, xq1, xq2, xq3;
  {
    const f32x4* pv = (const f32x4*)xroot;
    xq0 = pv[0]; xq1 = pv[1]; xq2 = pv[8]; xq3 = pv[9];
  }
  f32x4 cR, cZ, cXN;  // x-side gate tiles for the *next* step, register-resident
  {
    union { uint32_t u[4]; bf16x8 v; } x0, x1;
    x0.u[0] = cvtpk(xq0[0], xq0[1]); x0.u[1] = cvtpk(xq0[2], xq0[3]);
    x0.u[2] = cvtpk(xq1[0], xq1[1]); x0.u[3] = cvtpk(xq1[2], xq1[3]);
    x1.u[0] = cvtpk(xq2[0], xq2[1]); x1.u[1] = cvtpk(xq2[2], xq2[3]);
    x1.u[2] = cvtpk(xq3[0], xq3[1]); x1.u[3] = cvtpk(xq3[2], xq3[3]);
    cR  = __builtin_amdgcn_mfma_f32_16x16x32_bf16(wih[0][0], x0.v, biasR, 0, 0, 0);
    cR  = __builtin_amdgcn_mfma_f32_16x16x32_bf16(wih[0][1], x1.v, cR, 0, 0, 0);
    cZ  = __builtin_amdgcn_mfma_f32_16x16x32_bf16(wih[1][0], x0.v, biasZ, 0, 0, 0);
    cZ  = __builtin_amdgcn_mfma_f32_16x16x32_bf16(wih[1][1], x1.v, cZ, 0, 0, 0);
    cXN = __builtin_amdgcn_mfma_f32_16x16x32_bf16(wih[2][0], x0.v, biasXN, 0, 0, 0);
    cXN = __builtin_amdgcn_mfma_f32_16x16x32_bf16(wih[2][1], x1.v, cXN, 0, 0, 0);
  }
  // issue x[1] loads (consumed in t=0's x-phase)
  {
    const f32x4* pv = (const f32x4*)(xroot + (size_t)BB * HH);
    xq0 = pv[0]; xq1 = pv[1]; xq2 = pv[8]; xq3 = pv[9];
  }

  f32x4 hfp = {0.f, 0.f, 0.f, 0.f};  // fp32 h state (batch llo, 4 j's)
  block_sync_lds();

  for (int t = 0; t < TT; ++t) {
    const int buf = t & 1;
    // h B-frags from LDS (the only critical-path LDS)
    const bf16x8 hb0 = *(const bf16x8*)&hsh[buf][llo][k0];
    const bf16x8 hb1 = *(const bf16x8*)&hsh[buf][llo][k0 + 32];
    // h-side MFMAs accumulate onto register-resident x-tiles
    f32x4 aR  = __builtin_amdgcn_mfma_f32_16x16x32_bf16(whh[0][0], hb0, cR, 0, 0, 0);
    aR        = __builtin_amdgcn_mfma_f32_16x16x32_bf16(whh[0][1], hb1, aR, 0, 0, 0);
    f32x4 aZ  = __builtin_amdgcn_mfma_f32_16x16x32_bf16(whh[1][0], hb0, cZ, 0, 0, 0);
    aZ        = __builtin_amdgcn_mfma_f32_16x16x32_bf16(whh[1][1], hb1, aZ, 0, 0, 0);
    f32x4 aHN = __builtin_amdgcn_mfma_f32_16x16x32_bf16(whh[2][0], hb0, biasHN, 0, 0, 0);
    aHN       = __builtin_amdgcn_mfma_f32_16x16x32_bf16(whh[2][1], hb1, aHN, 0, 0, 0);
    const f32x4 aXN = cXN;

    // fp32 gate math + state update (lane-local)
#pragma unroll
    for (int r = 0; r < 4; ++r) {
      const float rr = sigm(aR[r]);
      const float zz = sigm(aZ[r]);
      const float nn = tanhf_fast(aXN[r] + rr * aHN[r]);
      hfp[r] = nn + zz * (hfp[r] - nn);
    }
    uint2 pk;
    pk.x = cvtpk(hfp[0], hfp[1]);
    pk.y = cvtpk(hfp[2], hfp[3]);
    *(uint2*)&hsh[buf ^ 1][llo][16 * w + 4 * lhi] = pk;

    // x-phase (off the h-critical path): tiles for t+1 from x[t+1] in regs
    union { uint32_t u[4]; bf16x8 v; } x0, x1;
    x0.u[0] = cvtpk(xq0[0], xq0[1]); x0.u[1] = cvtpk(xq0[2], xq0[3]);
    x0.u[2] = cvtpk(xq1[0], xq1[1]); x0.u[3] = cvtpk(xq1[2], xq1[3]);
    x1.u[0] = cvtpk(xq2[0], xq2[1]); x1.u[1] = cvtpk(xq2[2], xq2[3]);
    x1.u[2] = cvtpk(xq3[0], xq3[1]); x1.u[3] = cvtpk(xq3[2], xq3[3]);
    cR  = __builtin_amdgcn_mfma_f32_16x16x32_bf16(wih[0][0], x0.v, biasR, 0, 0, 0);
    cR  = __builtin_amdgcn_mfma_f32_16x16x32_bf16(wih[0][1], x1.v, cR, 0, 0, 0);
    cZ  = __builtin_amdgcn_mfma_f32_16x16x32_bf16(wih[1][0], x0.v, biasZ, 0, 0, 0);
    cZ  = __builtin_amdgcn_mfma_f32_16x16x32_bf16(wih[1][1], x1.v, cZ, 0, 0, 0);
    cXN = __builtin_amdgcn_mfma_f32_16x16x32_bf16(wih[2][0], x0.v, biasXN, 0, 0, 0);
    cXN = __builtin_amdgcn_mfma_f32_16x16x32_bf16(wih[2][1], x1.v, cXN, 0, 0, 0);
    // issue x[t+2] loads (clamped at tail; stay in flight across the barrier)
    {
      const int tn = (t + 2 < TT) ? t + 2 : TT - 1;
      const f32x4* pv = (const f32x4*)(xroot + (size_t)tn * BB * HH);
      xq0 = pv[0]; xq1 = pv[1]; xq2 = pv[8]; xq3 = pv[9];
    }
    block_sync_lds();
  }

  // ---- head: out[b] = h_last[b,:] . W_out + b_out ----
  {
    float part = 0.f;
#pragma unroll
    for (int r = 0; r < 4; ++r) part += hfp[r] * W_out[16 * w + 4 * lhi + r];
    part += __shfl_xor(part, 16);
    part += __shfl_xor(part, 32);
    if (lhi == 0) psum[w][llo] = part;
  }
  block_sync_lds();
  if (tid < BC)
    out[bbase + tid] = psum[0][tid] + psum[1][tid] + psum[2][tid] + psum[3][tid] + b_out[0];
}

extern "C" void kernel_launch(void* const* d_in, const int* in_sizes, int n_in,
                              void* d_out, int out_size, void* d_ws, size_t ws_size,
                              hipStream_t stream) {
  (void)in_sizes; (void)n_in; (void)d_ws; (void)ws_size; (void)out_size;
  const float* Hseq  = (const float*)d_in[0];
  const float* W_ih  = (const float*)d_in[1];
  const float* W_hh  = (const float*)d_in[2];
  const float* b_ih  = (const float*)d_in[3];
  const float* b_hh  = (const float*)d_in[4];
  const float* W_out = (const float*)d_in[5];
  const float* b_out = (const float*)d_in[6];
  float* out = (float*)d_out;
  gru_fused<<<BB / BC, 256, 0, stream>>>(Hseq, W_ih, W_hh, b_ih, b_hh, W_out, b_out, out);
}

// Round 7
// 68.065 us; speedup vs baseline: 1.2252x; 1.2252x over previous
//
#include <hip/hip_runtime.h>
#include <stdint.h>

#define TT 128
#define BB 4096
#define HH 64
#define BC 16      // batch rows per block
#define XSTR 196   // xg LDS row stride (floats); 49 dwords -> conflict-light
#define HSTR 72    // h LDS row stride (bf16 shorts): 144B rows, 16B aligned

typedef __attribute__((ext_vector_type(8))) short bf16x8;
typedef __attribute__((ext_vector_type(4))) float f32x4;

static __device__ __forceinline__ short f2bf(float f) {  // RNE, one-time W convert
  uint32_t u = __builtin_bit_cast(uint32_t, f);
  u += 0x7fffu + ((u >> 16) & 1u);
  return (short)(u >> 16);
}
static __device__ __forceinline__ uint32_t cvtpk(float a, float b) {
  uint32_t r;
  asm("v_cvt_pk_bf16_f32 %0, %1, %2" : "=v"(r) : "v"(a), "v"(b));
  return r;  // lo16 = bf16(a), hi16 = bf16(b)
}
static __device__ __forceinline__ float rcpf(float x) { return __builtin_amdgcn_rcpf(x); }
static __device__ __forceinline__ float sigm(float x) { return rcpf(1.0f + __expf(-x)); }
static __device__ __forceinline__ float tanhf_fast(float x) {
  float e = __expf(2.0f * x);
  return 1.0f - 2.0f * rcpf(e + 1.0f);
}

// lgkm-only barrier: LDS ops drain, global prefetch loads stay in flight.
static __device__ __forceinline__ void block_sync_lds() {
  asm volatile("" ::: "memory");
  asm volatile("s_waitcnt lgkmcnt(0)" ::: "memory");
  __builtin_amdgcn_s_barrier();
  asm volatile("" ::: "memory");
}

__global__ __launch_bounds__(512) void gru_fused(
    const float* __restrict__ Hseq, const float* __restrict__ W_ih,
    const float* __restrict__ W_hh, const float* __restrict__ b_ih,
    const float* __restrict__ b_hh, const float* __restrict__ W_out,
    const float* __restrict__ b_out, float* __restrict__ out) {
  __shared__ __align__(16) short hsh[2][BC][HSTR];   // bf16 h state, double buffered
  __shared__ __align__(16) float xgsh[2][BC][XSTR];  // fp32 x-side gate preacts
  __shared__ float psum[4][BC];

  const int tid = threadIdx.x;
  const int w   = tid >> 6;     // 0..7; 0-3 consumers (recurrence), 4-7 producers (x GEMM)
  const int gw  = w & 3;        // gate-row chunk: j in [16gw, 16gw+16)
  const bool cons = (w < 4);
  const int l   = tid & 63;
  const int llo = l & 15;       // batch col (B/D frags) or gate row (A frag)
  const int lhi = l >> 4;
  const int k0  = lhi * 8;
  const int bbase = blockIdx.x * BC;

  // zero h buffer 0 (h0 = 0)
  for (int i = tid; i < BC * HSTR; i += 512) ((short*)hsh[0])[i] = 0;

  bf16x8 wa[3][2];                       // consumer: W_hh frags; producer: W_ih frags
  f32x4 biasHN = {0, 0, 0, 0};           // consumer only
  f32x4 biasPR = {0, 0, 0, 0}, biasPZ = {0, 0, 0, 0}, biasPN = {0, 0, 0, 0};  // producer

  if (cons) {
#pragma unroll
    for (int c = 0; c < 3; ++c) {
      const int grow = 16 * gw + 64 * c + llo;
#pragma unroll
      for (int hf = 0; hf < 2; ++hf) {
        const float* q = &W_hh[grow * 64 + hf * 32 + k0];
        bf16x8 b;
#pragma unroll
        for (int i = 0; i < 8; ++i) b[i] = f2bf(q[i]);
        wa[c][hf] = b;
      }
    }
#pragma unroll
    for (int r = 0; r < 4; ++r) biasHN[r] = b_hh[128 + 16 * gw + 4 * lhi + r];
  } else {
#pragma unroll
    for (int c = 0; c < 3; ++c) {
      const int grow = 16 * gw + 64 * c + llo;
#pragma unroll
      for (int hf = 0; hf < 2; ++hf) {
        const float* p = &W_ih[grow * 64 + hf * 32 + k0];
        bf16x8 a;
#pragma unroll
        for (int i = 0; i < 8; ++i) a[i] = f2bf(p[i]);
        wa[c][hf] = a;
      }
    }
#pragma unroll
    for (int r = 0; r < 4; ++r) {
      const int j = 16 * gw + 4 * lhi + r;
      biasPR[r] = b_ih[j] + b_hh[j];
      biasPZ[r] = b_ih[64 + j] + b_hh[64 + j];
      biasPN[r] = b_ih[128 + j];
    }
  }

  const float* xroot = Hseq + (size_t)(bbase + llo) * HH + k0;  // per-lane t=0 base
  // producer 2-deep prefetch register sets (consumers never touch these)
  f32x4 xqA0, xqA1, xqA2, xqA3, xqB0, xqB1, xqB2, xqB3;
  f32x4 hfp = {0.f, 0.f, 0.f, 0.f};  // consumer fp32 h (batch llo, 4 j's)

  // producer pre-step: xg[0] into buffer 0, then prefetch x[1] and x[2]
  if (!cons) {
    const f32x4* pv = (const f32x4*)xroot;  // x[0]
    f32x4 q0 = pv[0], q1 = pv[1], q2 = pv[8], q3 = pv[9];
    union { uint32_t u[4]; bf16x8 v; } c0, c1;
    c0.u[0] = cvtpk(q0[0], q0[1]); c0.u[1] = cvtpk(q0[2], q0[3]);
    c0.u[2] = cvtpk(q1[0], q1[1]); c0.u[3] = cvtpk(q1[2], q1[3]);
    c1.u[0] = cvtpk(q2[0], q2[1]); c1.u[1] = cvtpk(q2[2], q2[3]);
    c1.u[2] = cvtpk(q3[0], q3[1]); c1.u[3] = cvtpk(q3[2], q3[3]);
    f32x4 cR = biasPR, cZ = biasPZ, cN = biasPN;
    cR = __builtin_amdgcn_mfma_f32_16x16x32_bf16(wa[0][0], c0.v, cR, 0, 0, 0);
    cR = __builtin_amdgcn_mfma_f32_16x16x32_bf16(wa[0][1], c1.v, cR, 0, 0, 0);
    cZ = __builtin_amdgcn_mfma_f32_16x16x32_bf16(wa[1][0], c0.v, cZ, 0, 0, 0);
    cZ = __builtin_amdgcn_mfma_f32_16x16x32_bf16(wa[1][1], c1.v, cZ, 0, 0, 0);
    cN = __builtin_amdgcn_mfma_f32_16x16x32_bf16(wa[2][0], c0.v, cN, 0, 0, 0);
    cN = __builtin_amdgcn_mfma_f32_16x16x32_bf16(wa[2][1], c1.v, cN, 0, 0, 0);
    *(f32x4*)&xgsh[0][llo][16 * gw + 4 * lhi]       = cR;
    *(f32x4*)&xgsh[0][llo][64 + 16 * gw + 4 * lhi]  = cZ;
    *(f32x4*)&xgsh[0][llo][128 + 16 * gw + 4 * lhi] = cN;
    const f32x4* pa = (const f32x4*)(xroot + (size_t)1 * BB * HH);  // x[1]
    xqA0 = pa[0]; xqA1 = pa[1]; xqA2 = pa[8]; xqA3 = pa[9];
    const f32x4* pb = (const f32x4*)(xroot + (size_t)2 * BB * HH);  // x[2]
    xqB0 = pb[0]; xqB1 = pb[1]; xqB2 = pb[8]; xqB3 = pb[9];
  }
  block_sync_lds();

  for (int t = 0; t < TT; t += 2) {
    // ================= step t (even): buf = 0 =================
    if (cons) {
      f32x4 aR  = *(const f32x4*)&xgsh[0][llo][16 * gw + 4 * lhi];
      f32x4 aZ  = *(const f32x4*)&xgsh[0][llo][64 + 16 * gw + 4 * lhi];
      f32x4 aXN = *(const f32x4*)&xgsh[0][llo][128 + 16 * gw + 4 * lhi];
      f32x4 aHN = biasHN;
      const bf16x8 hb0 = *(const bf16x8*)&hsh[0][llo][k0];
      const bf16x8 hb1 = *(const bf16x8*)&hsh[0][llo][k0 + 32];
      aR  = __builtin_amdgcn_mfma_f32_16x16x32_bf16(wa[0][0], hb0, aR, 0, 0, 0);
      aR  = __builtin_amdgcn_mfma_f32_16x16x32_bf16(wa[0][1], hb1, aR, 0, 0, 0);
      aZ  = __builtin_amdgcn_mfma_f32_16x16x32_bf16(wa[1][0], hb0, aZ, 0, 0, 0);
      aZ  = __builtin_amdgcn_mfma_f32_16x16x32_bf16(wa[1][1], hb1, aZ, 0, 0, 0);
      aHN = __builtin_amdgcn_mfma_f32_16x16x32_bf16(wa[2][0], hb0, aHN, 0, 0, 0);
      aHN = __builtin_amdgcn_mfma_f32_16x16x32_bf16(wa[2][1], hb1, aHN, 0, 0, 0);
#pragma unroll
      for (int r = 0; r < 4; ++r) {
        const float rr = sigm(aR[r]);
        const float zz = sigm(aZ[r]);
        const float nn = tanhf_fast(aXN[r] + rr * aHN[r]);
        hfp[r] = nn + zz * (hfp[r] - nn);
      }
      uint2 pk;
      pk.x = cvtpk(hfp[0], hfp[1]);
      pk.y = cvtpk(hfp[2], hfp[3]);
      *(uint2*)&hsh[1][llo][16 * gw + 4 * lhi] = pk;
    } else {
      // produce xg[t+1] into xgsh[1] from xqA (= x[t+1]); refill xqA <- x[t+3]
      union { uint32_t u[4]; bf16x8 v; } c0, c1;
      c0.u[0] = cvtpk(xqA0[0], xqA0[1]); c0.u[1] = cvtpk(xqA0[2], xqA0[3]);
      c0.u[2] = cvtpk(xqA1[0], xqA1[1]); c0.u[3] = cvtpk(xqA1[2], xqA1[3]);
      c1.u[0] = cvtpk(xqA2[0], xqA2[1]); c1.u[1] = cvtpk(xqA2[2], xqA2[3]);
      c1.u[2] = cvtpk(xqA3[0], xqA3[1]); c1.u[3] = cvtpk(xqA3[2], xqA3[3]);
      {
        const int tn = (t + 3 < TT) ? (t + 3) : (TT - 1);
        const f32x4* pv = (const f32x4*)(xroot + (size_t)tn * BB * HH);
        xqA0 = pv[0]; xqA1 = pv[1]; xqA2 = pv[8]; xqA3 = pv[9];
      }
      f32x4 cR = biasPR, cZ = biasPZ, cN = biasPN;
      cR = __builtin_amdgcn_mfma_f32_16x16x32_bf16(wa[0][0], c0.v, cR, 0, 0, 0);
      cR = __builtin_amdgcn_mfma_f32_16x16x32_bf16(wa[0][1], c1.v, cR, 0, 0, 0);
      cZ = __builtin_amdgcn_mfma_f32_16x16x32_bf16(wa[1][0], c0.v, cZ, 0, 0, 0);
      cZ = __builtin_amdgcn_mfma_f32_16x16x32_bf16(wa[1][1], c1.v, cZ, 0, 0, 0);
      cN = __builtin_amdgcn_mfma_f32_16x16x32_bf16(wa[2][0], c0.v, cN, 0, 0, 0);
      cN = __builtin_amdgcn_mfma_f32_16x16x32_bf16(wa[2][1], c1.v, cN, 0, 0, 0);
      *(f32x4*)&xgsh[1][llo][16 * gw + 4 * lhi]       = cR;
      *(f32x4*)&xgsh[1][llo][64 + 16 * gw + 4 * lhi]  = cZ;
      *(f32x4*)&xgsh[1][llo][128 + 16 * gw + 4 * lhi] = cN;
    }
    block_sync_lds();

    // ================= step t+1 (odd): buf = 1 =================
    if (cons) {
      f32x4 aR  = *(const f32x4*)&xgsh[1][llo][16 * gw + 4 * lhi];
      f32x4 aZ  = *(const f32x4*)&xgsh[1][llo][64 + 16 * gw + 4 * lhi];
      f32x4 aXN = *(const f32x4*)&xgsh[1][llo][128 + 16 * gw + 4 * lhi];
      f32x4 aHN = biasHN;
      const bf16x8 hb0 = *(const bf16x8*)&hsh[1][llo][k0];
      const bf16x8 hb1 = *(const bf16x8*)&hsh[1][llo][k0 + 32];
      aR  = __builtin_amdgcn_mfma_f32_16x16x32_bf16(wa[0][0], hb0, aR, 0, 0, 0);
      aR  = __builtin_amdgcn_mfma_f32_16x16x32_bf16(wa[0][1], hb1, aR, 0, 0, 0);
      aZ  = __builtin_amdgcn_mfma_f32_16x16x32_bf16(wa[1][0], hb0, aZ, 0, 0, 0);
      aZ  = __builtin_amdgcn_mfma_f32_16x16x32_bf16(wa[1][1], hb1, aZ, 0, 0, 0);
      aHN = __builtin_amdgcn_mfma_f32_16x16x32_bf16(wa[2][0], hb0, aHN, 0, 0, 0);
      aHN = __builtin_amdgcn_mfma_f32_16x16x32_bf16(wa[2][1], hb1, aHN, 0, 0, 0);
#pragma unroll
      for (int r = 0; r < 4; ++r) {
        const float rr = sigm(aR[r]);
        const float zz = sigm(aZ[r]);
        const float nn = tanhf_fast(aXN[r] + rr * aHN[r]);
        hfp[r] = nn + zz * (hfp[r] - nn);
      }
      uint2 pk;
      pk.x = cvtpk(hfp[0], hfp[1]);
      pk.y = cvtpk(hfp[2], hfp[3]);
      *(uint2*)&hsh[0][llo][16 * gw + 4 * lhi] = pk;
    } else {
      // produce xg[t+2] into xgsh[0] from xqB (= x[t+2]); refill xqB <- x[t+4]
      union { uint32_t u[4]; bf16x8 v; } c0, c1;
      c0.u[0] = cvtpk(xqB0[0], xqB0[1]); c0.u[1] = cvtpk(xqB0[2], xqB0[3]);
      c0.u[2] = cvtpk(xqB1[0], xqB1[1]); c0.u[3] = cvtpk(xqB1[2], xqB1[3]);
      c1.u[0] = cvtpk(xqB2[0], xqB2[1]); c1.u[1] = cvtpk(xqB2[2], xqB2[3]);
      c1.u[2] = cvtpk(xqB3[0], xqB3[1]); c1.u[3] = cvtpk(xqB3[2], xqB3[3]);
      {
        const int tn = (t + 4 < TT) ? (t + 4) : (TT - 1);
        const f32x4* pv = (const f32x4*)(xroot + (size_t)tn * BB * HH);
        xqB0 = pv[0]; xqB1 = pv[1]; xqB2 = pv[8]; xqB3 = pv[9];
      }
      f32x4 cR = biasPR, cZ = biasPZ, cN = biasPN;
      cR = __builtin_amdgcn_mfma_f32_16x16x32_bf16(wa[0][0], c0.v, cR, 0, 0, 0);
      cR = __builtin_amdgcn_mfma_f32_16x16x32_bf16(wa[0][1], c1.v, cR, 0, 0, 0);
      cZ = __builtin_amdgcn_mfma_f32_16x16x32_bf16(wa[1][0], c0.v, cZ, 0, 0, 0);
      cZ = __builtin_amdgcn_mfma_f32_16x16x32_bf16(wa[1][1], c1.v, cZ, 0, 0, 0);
      cN = __builtin_amdgcn_mfma_f32_16x16x32_bf16(wa[2][0], c0.v, cN, 0, 0, 0);
      cN = __builtin_amdgcn_mfma_f32_16x16x32_bf16(wa[2][1], c1.v, cN, 0, 0, 0);
      *(f32x4*)&xgsh[0][llo][16 * gw + 4 * lhi]       = cR;
      *(f32x4*)&xgsh[0][llo][64 + 16 * gw + 4 * lhi]  = cZ;
      *(f32x4*)&xgsh[0][llo][128 + 16 * gw + 4 * lhi] = cN;
    }
    block_sync_lds();
  }

  // ---- head: out[b] = h_last[b,:] . W_out + b_out ----
  if (cons) {
    float part = 0.f;
#pragma unroll
    for (int r = 0; r < 4; ++r) part += hfp[r] * W_out[16 * gw + 4 * lhi + r];
    part += __shfl_xor(part, 16);
    part += __shfl_xor(part, 32);
    if (lhi == 0) psum[gw][llo] = part;
  }
  block_sync_lds();
  if (tid < BC)
    out[bbase + tid] = psum[0][tid] + psum[1][tid] + psum[2][tid] + psum[3][tid] + b_out[0];
}

extern "C" void kernel_launch(void* const* d_in, const int* in_sizes, int n_in,
                              void* d_out, int out_size, void* d_ws, size_t ws_size,
                              hipStream_t stream) {
  (void)in_sizes; (void)n_in; (void)d_ws; (void)ws_size; (void)out_size;
  const float* Hseq  = (const float*)d_in[0];
  const float* W_ih  = (const float*)d_in[1];
  const float* W_hh  = (const float*)d_in[2];
  const float* b_ih  = (const float*)d_in[3];
  const float* b_hh  = (const float*)d_in[4];
  const float* W_out = (const float*)d_in[5];
  const float* b_out = (const float*)d_in[6];
  float* out = (float*)d_out;
  gru_fused<<<BB / BC, 512, 0, stream>>>(Hseq, W_ih, W_hh, b_ih, b_hh, W_out, b_out, out);
}